// Round 6
// baseline (534.590 us; speedup 1.0000x reference)
//
#include <hip/hip_runtime.h>

#define B_N   262144
#define PMIN_F 0.001f
#define LOG2E 1.44269504088896340736f
#define LN2   0.69314718055994530942f

typedef _Float16 half4v __attribute__((ext_vector_type(4)));
typedef _Float16 half8  __attribute__((ext_vector_type(8)));
typedef float    floatx4 __attribute__((ext_vector_type(4)));

__device__ __forceinline__ float fexp2(float x) { return __builtin_amdgcn_exp2f(x); }
__device__ __forceinline__ float flog2(float x) { return __builtin_amdgcn_logf(x); }
__device__ __forceinline__ float frcp (float x) { return __builtin_amdgcn_rcpf(x); }

// ---------------------------------------------------------------------------
// Prep: weights fp32 -> f16 in MFMA B-fragment order (unchanged from R5).
// Fragment (ntile, kstep): lane (kg=lane>>4, c=lane&15) holds 8 halves
// B[kstep*32 + kg*8 + j][ntile*16 + c], j=0..7.
//   r in [0,8)   : mm1 W1 16x128, K padded to 32; k==16 row carries b1
//   r in [8,40)  : mm2 Wh 128x128
//   r in [40,104): mm3 Wo 128x248 column-remapped to 256 (31->32 pad per d)
// ---------------------------------------------------------------------------
__global__ __launch_bounds__(64) void prep_kernel(
    const float* __restrict__ W1s, const float* __restrict__ b1s,
    const float* __restrict__ Whs, const float* __restrict__ Wos,
    _Float16* __restrict__ ws)
{
    const int bid   = blockIdx.x;          // 0..415
    const int layer = bid / 104;
    const int r     = bid % 104;
    const int lane  = threadIdx.x;
    const int kg    = lane >> 4;
    const int c     = lane & 15;

    half8 v;
    if (r < 8) {
        const int nt = r, n = nt * 16 + c;
        const float* W1 = W1s + layer * 16 * 128;
        const float* b1 = b1s + layer * 128;
        #pragma unroll
        for (int j = 0; j < 8; ++j) {
            const int k = kg * 8 + j;
            v[j] = (k < 16) ? (_Float16)W1[k * 128 + n]
                 : (k == 16) ? (_Float16)b1[n] : (_Float16)0.f;
        }
    } else if (r < 40) {
        const int f = r - 8, nt = f >> 2, ks = f & 3, n = nt * 16 + c;
        const float* Wh = Whs + layer * 128 * 128;
        #pragma unroll
        for (int j = 0; j < 8; ++j) {
            const int k = ks * 32 + kg * 8 + j;
            v[j] = (_Float16)Wh[k * 128 + n];
        }
    } else {
        const int f = r - 40, nt = f >> 2, ks = f & 3, n = nt * 16 + c;
        const int dd = n >> 5, cc = n & 31;
        const float* Wo = Wos + layer * 128 * 248;
        #pragma unroll
        for (int j = 0; j < 8; ++j) {
            const int k = ks * 32 + kg * 8 + j;
            v[j] = (cc < 31) ? (_Float16)Wo[k * 248 + dd * 31 + cc] : (_Float16)0.f;
        }
    }
    *(half8*)(ws + (size_t)bid * 512 + lane * 8) = v;
}

// ---------------------------------------------------------------------------
// Main: one wave = 32 rows (2 tiles). Single 16x132 R buffer per tile reused
// h1 -> h2 -> theta-half (A-frags pulled to regs before each overwrite);
// mm3+spline split into 2 half-passes (d=0..3, d=4..7).
// LDS/WG = 2*(1KB xls + 256B cls + 4.125KB R) = 11 KB -> 14 WGs/CU.
// __launch_bounds__(64,4): cap VGPR at 128 (waves/SIMD cliff).
// ---------------------------------------------------------------------------
__global__ __launch_bounds__(64, 4) void flow_mfma(
    const float* __restrict__ x_in,
    const float* __restrict__ c_in,
    const float* __restrict__ bhs,
    const float* __restrict__ bos,
    const int*   __restrict__ perms,
    const _Float16* __restrict__ wsW,
    float* __restrict__ out)
{
    __shared__ __align__(16) float    xls[2][256];   // [tile][16 rows][16]
    __shared__ __align__(16) _Float16 cls[2][128];   // [tile][16 rows][8]
    __shared__ __align__(16) _Float16 R[2][2112];    // h1 / h2 / theta-half, stride 132

    const int lane = threadIdx.x;
    const int q    = lane >> 4;
    const int m    = lane & 15;
    const long long row0 = (long long)blockIdx.x * 32;

    {
        const float4* xp = (const float4*)(x_in + row0 * 16);
        *(float4*)&xls[0][lane * 4] = xp[lane];
        *(float4*)&xls[1][lane * 4] = xp[lane + 64];
        const float2* cp = (const float2*)(c_in + row0 * 8);
        const float2 c0 = cp[lane], c1 = cp[lane + 64];
        cls[0][lane * 2]     = (_Float16)c0.x;
        cls[0][lane * 2 + 1] = (_Float16)c0.y;
        cls[1][lane * 2]     = (_Float16)c1.x;
        cls[1][lane * 2 + 1] = (_Float16)c1.y;
    }
    __syncthreads();

    float ljrow[2] = {0.f, 0.f};

    for (int l = 0; l < 4; ++l) {
        const _Float16* wsl = wsW + (size_t)l * 104 * 512;
        const float* bh = bhs + l * 128;
        const float* bo = bos + l * 248;

        // ================= mm1: [x1,c,1] @ [W1;b1] -> h1 =================
        half8 a1[2];
        #pragma unroll
        for (int t2 = 0; t2 < 2; ++t2) {
            #pragma unroll
            for (int j = 0; j < 8; ++j) a1[t2][j] = (_Float16)0.f;
            if (q == 0) {
                const float4 lo = *(const float4*)&xls[t2][m * 16];
                const float4 hi = *(const float4*)&xls[t2][m * 16 + 4];
                a1[t2][0] = (_Float16)lo.x; a1[t2][1] = (_Float16)lo.y;
                a1[t2][2] = (_Float16)lo.z; a1[t2][3] = (_Float16)lo.w;
                a1[t2][4] = (_Float16)hi.x; a1[t2][5] = (_Float16)hi.y;
                a1[t2][6] = (_Float16)hi.z; a1[t2][7] = (_Float16)hi.w;
            } else if (q == 1) {
                a1[t2] = *(const half8*)&cls[t2][m * 8];
            } else if (q == 2) {
                a1[t2][0] = (_Float16)1.f;   // k=16 -> bias row
            }
        }
        {
            const floatx4 z = {0.f, 0.f, 0.f, 0.f};
            floatx4 acc0[8], acc1[8];
            #pragma unroll
            for (int nt = 0; nt < 8; ++nt) {
                const half8 b = *(const half8*)(wsl + nt * 512 + lane * 8);
                acc0[nt] = __builtin_amdgcn_mfma_f32_16x16x32_f16(a1[0], b, z, 0, 0, 0);
                acc1[nt] = __builtin_amdgcn_mfma_f32_16x16x32_f16(a1[1], b, z, 0, 0, 0);
            }
            #pragma unroll
            for (int nt = 0; nt < 8; ++nt)
                #pragma unroll
                for (int reg = 0; reg < 4; ++reg) {
                    R[0][(q * 4 + reg) * 132 + nt * 16 + m] = (_Float16)fmaxf(acc0[nt][reg], 0.f);
                    R[1][(q * 4 + reg) * 132 + nt * 16 + m] = (_Float16)fmaxf(acc1[nt][reg], 0.f);
                }
        }
        __syncthreads();

        // ===== mm2: pull h1 A-frags to regs, then overwrite region with h2 =====
        half8 a2[2][4];
        #pragma unroll
        for (int t2 = 0; t2 < 2; ++t2)
            #pragma unroll
            for (int ks = 0; ks < 4; ++ks) {
                const half4v lo = *(const half4v*)&R[t2][m * 132 + ks * 32 + q * 8];
                const half4v hi = *(const half4v*)&R[t2][m * 132 + ks * 32 + q * 8 + 4];
                a2[t2][ks] = __builtin_shufflevector(lo, hi, 0, 1, 2, 3, 4, 5, 6, 7);
            }
        __syncthreads();
        {
            floatx4 acc0[8], acc1[8];
            #pragma unroll
            for (int nt = 0; nt < 8; ++nt) {
                const float bb = bh[nt * 16 + m];
                acc0[nt][0] = bb; acc0[nt][1] = bb; acc0[nt][2] = bb; acc0[nt][3] = bb;
                acc1[nt] = acc0[nt];
            }
            #pragma unroll
            for (int ks = 0; ks < 4; ++ks)
                #pragma unroll
                for (int nt = 0; nt < 8; ++nt) {
                    const half8 b = *(const half8*)(wsl + (8 + nt * 4 + ks) * 512 + lane * 8);
                    acc0[nt] = __builtin_amdgcn_mfma_f32_16x16x32_f16(a2[0][ks], b, acc0[nt], 0, 0, 0);
                    acc1[nt] = __builtin_amdgcn_mfma_f32_16x16x32_f16(a2[1][ks], b, acc1[nt], 0, 0, 0);
                }
            #pragma unroll
            for (int nt = 0; nt < 8; ++nt)
                #pragma unroll
                for (int reg = 0; reg < 4; ++reg) {
                    R[0][(q * 4 + reg) * 132 + nt * 16 + m] = (_Float16)fmaxf(acc0[nt][reg], 0.f);
                    R[1][(q * 4 + reg) * 132 + nt * 16 + m] = (_Float16)fmaxf(acc1[nt][reg], 0.f);
                }
        }
        __syncthreads();

        // ===== mm3: pull h2 A-frags to regs; theta halves overwrite region =====
        half8 a3[2][4];
        #pragma unroll
        for (int t2 = 0; t2 < 2; ++t2)
            #pragma unroll
            for (int ks = 0; ks < 4; ++ks) {
                const half4v lo = *(const half4v*)&R[t2][m * 132 + ks * 32 + q * 8];
                const half4v hi = *(const half4v*)&R[t2][m * 132 + ks * 32 + q * 8 + 4];
                a3[t2][ks] = __builtin_shufflevector(lo, hi, 0, 1, 2, 3, 4, 5, 6, 7);
            }
        __syncthreads();

        #pragma unroll
        for (int hf = 0; hf < 2; ++hf) {
            // ---- mm3 half: cols [hf*128, hf*128+128) = d in [hf*4, hf*4+4)
            {
                floatx4 acc0[8], acc1[8];
                #pragma unroll
                for (int nt8 = 0; nt8 < 8; ++nt8) {
                    const int nt = hf * 8 + nt8;
                    const float bb = ((nt & 1) && m == 15) ? 0.f
                                   : bo[(nt >> 1) * 31 + (nt & 1) * 16 + m];
                    acc0[nt8][0] = bb; acc0[nt8][1] = bb; acc0[nt8][2] = bb; acc0[nt8][3] = bb;
                    acc1[nt8] = acc0[nt8];
                }
                #pragma unroll
                for (int ks = 0; ks < 4; ++ks)
                    #pragma unroll
                    for (int nt8 = 0; nt8 < 8; ++nt8) {
                        const int nt = hf * 8 + nt8;
                        const half8 b = *(const half8*)(wsl + (40 + nt * 4 + ks) * 512 + lane * 8);
                        acc0[nt8] = __builtin_amdgcn_mfma_f32_16x16x32_f16(a3[0][ks], b, acc0[nt8], 0, 0, 0);
                        acc1[nt8] = __builtin_amdgcn_mfma_f32_16x16x32_f16(a3[1][ks], b, acc1[nt8], 0, 0, 0);
                    }
                #pragma unroll
                for (int nt8 = 0; nt8 < 8; ++nt8)
                    #pragma unroll
                    for (int reg = 0; reg < 4; ++reg) {
                        R[0][(q * 4 + reg) * 132 + nt8 * 16 + m] = (_Float16)acc0[nt8][reg];
                        R[1][(q * 4 + reg) * 132 + nt8 * 16 + m] = (_Float16)acc1[nt8][reg];
                    }
            }
            __syncthreads();

            // ---- spline half-pass: 128 items (2 tiles x 16 rows x 4 d)
            #pragma unroll
            for (int itp = 0; itp < 2; ++itp) {
                const int t2   = itp;
                const int row  = lane >> 2;
                const int dloc = lane & 3;
                const int d    = hf * 4 + dloc;
                const int base = row * 132 + dloc * 32;

                const half4v v0 = *(const half4v*)&R[t2][base];
                const half4v v1 = *(const half4v*)&R[t2][base + 4];
                const half4v v2 = *(const half4v*)&R[t2][base + 8];
                const half4v v3 = *(const half4v*)&R[t2][base + 12];
                const half4v v4 = *(const half4v*)&R[t2][base + 16];
                const float x2 = xls[t2][row * 16 + 8 + d];

                float tw[10];
                tw[0]=(float)v0[0]; tw[1]=(float)v0[1]; tw[2]=(float)v0[2]; tw[3]=(float)v0[3];
                tw[4]=(float)v1[0]; tw[5]=(float)v1[1]; tw[6]=(float)v1[2]; tw[7]=(float)v1[3];
                tw[8]=(float)v2[0]; tw[9]=(float)v2[1];

                float cx[11], cy[11];
                {
                    float m1 = tw[0];
                    #pragma unroll
                    for (int i = 1; i < 10; ++i) m1 = fmaxf(m1, tw[i]);
                    float se = 0.f;
                    #pragma unroll
                    for (int i = 0; i < 10; ++i) { tw[i] = fexp2((tw[i] - m1) * LOG2E); se += tw[i]; }
                    const float inv198 = 1.98f * frcp(se);   // 2*(1-PMIN*K)*inv
                    cx[0] = -1.f;
                    #pragma unroll
                    for (int i = 0; i < 10; ++i) cx[i + 1] = cx[i] + fmaf(tw[i], inv198, 0.002f);
                }
                {
                    float t0=(float)v2[2], t1=(float)v2[3];
                    float t2v=(float)v3[0], t3=(float)v3[1], t4=(float)v3[2], t5=(float)v3[3];
                    float t6=(float)v4[0], t7=(float)v4[1], t8=(float)v4[2], t9=(float)v4[3];
                    float hm = fmaxf(fmaxf(fmaxf(t0,t1),fmaxf(t2v,t3)),
                                     fmaxf(fmaxf(t4,t5),fmaxf(fmaxf(t6,t7),fmaxf(t8,t9))));
                    float e0=fexp2((t0-hm)*LOG2E), e1=fexp2((t1-hm)*LOG2E);
                    float e2=fexp2((t2v-hm)*LOG2E), e3=fexp2((t3-hm)*LOG2E);
                    float e4=fexp2((t4-hm)*LOG2E), e5=fexp2((t5-hm)*LOG2E);
                    float e6=fexp2((t6-hm)*LOG2E), e7=fexp2((t7-hm)*LOG2E);
                    float e8=fexp2((t8-hm)*LOG2E), e9=fexp2((t9-hm)*LOG2E);
                    const float se = ((e0+e1)+(e2+e3))+((e4+e5)+((e6+e7)+(e8+e9)));
                    const float inv198 = 1.98f * frcp(se);
                    cy[0] = -1.f;
                    cy[1] = cy[0] + fmaf(e0, inv198, 0.002f);
                    cy[2] = cy[1] + fmaf(e1, inv198, 0.002f);
                    cy[3] = cy[2] + fmaf(e2, inv198, 0.002f);
                    cy[4] = cy[3] + fmaf(e3, inv198, 0.002f);
                    cy[5] = cy[4] + fmaf(e4, inv198, 0.002f);
                    cy[6] = cy[5] + fmaf(e5, inv198, 0.002f);
                    cy[7] = cy[6] + fmaf(e6, inv198, 0.002f);
                    cy[8] = cy[7] + fmaf(e7, inv198, 0.002f);
                    cy[9] = cy[8] + fmaf(e8, inv198, 0.002f);
                    cy[10]= cy[9] + fmaf(e9, inv198, 0.002f);
                }

                int cnt = 0;
                #pragma unroll
                for (int i = 0; i < 11; ++i) cnt += (cx[i] < x2) ? 1 : 0;
                const int bidx = cnt - 1;
                const bool inb = (bidx >= 0) && (bidx < 10);
                const int ci = bidx < 0 ? 0 : (bidx > 9 ? 9 : bidx);

                float xlo = cx[0], xhi = cx[1], ylo = cy[0], yhi = cy[1];
                #pragma unroll
                for (int i = 1; i < 10; ++i) {
                    const bool pick = (i == ci);
                    xlo = pick ? cx[i]     : xlo;
                    xhi = pick ? cx[i + 1] : xhi;
                    ylo = pick ? cy[i]     : ylo;
                    yhi = pick ? cy[i + 1] : yhi;
                }
                const float xw = xhi - xlo, yw = yhi - ylo;
                const float rx = cx[10], ry = cy[10];

                // slopes: LDS-indexed read of the 2 needed raw params
                const float u1 = (float)R[t2][base + 20 + ci];
                const float u2 = (float)R[t2][base + 21 + ci];
                const float t1 = u1 * LOG2E;
                const float t2s = u2 * LOG2E;
                const float dd1 = PMIN_F + 0.999f * ((t1  > 15.f) ? t1  : flog2(1.f + fexp2(t1)));
                const float dd2 = PMIN_F + 0.999f * ((t2s > 15.f) ? t2s : flog2(1.f + fexp2(t2s)));

                const float xs  = inb ? x2 : (xlo + 0.5f * xw);
                const float rxw = frcp(xw);
                const float s   = yw * rxw;
                const float eta = (xs - xlo) * rxw;
                const float rev = 1.f - eta;
                const float er  = eta * rev;
                const float dn  = s + (dd1 + dd2 - 2.f * s) * er;
                const float yrq = ylo + yw * (s * eta * eta + dd1 * er) * frcp(dn);
                const float jn  = s * s * (dd2 * eta * eta + 2.f * s * er + dd1 * rev * rev);
                const float ljx = LN2 * (flog2(jn) - 2.f * flog2(dn));
                const float ylin = (ry + 1.f) * frcp(rx + 1.f) * (x2 + 1.f) - 1.f;

                xls[t2][row * 16 + 8 + d] = inb ? yrq : ylin;

                float lj = inb ? ljx : 0.f;
                lj += __shfl_xor(lj, 1);
                lj += __shfl_xor(lj, 2);
                ljrow[t2] += lj;
            }
            __syncthreads();
        }

        // ================= permutation =================
        {
            const int4 pv = ((const int4*)(perms + l * 16))[lane & 3];
            const int mm = lane >> 2;
            const float a0 = xls[0][mm * 16 + pv.x];
            const float a1v = xls[0][mm * 16 + pv.y];
            const float a2v = xls[0][mm * 16 + pv.z];
            const float a3v = xls[0][mm * 16 + pv.w];
            const float b0 = xls[1][mm * 16 + pv.x];
            const float b1v = xls[1][mm * 16 + pv.y];
            const float b2 = xls[1][mm * 16 + pv.z];
            const float b3 = xls[1][mm * 16 + pv.w];
            __syncthreads();
            *(float4*)&xls[0][lane * 4] = make_float4(a0, a1v, a2v, a3v);
            *(float4*)&xls[1][lane * 4] = make_float4(b0, b1v, b2, b3);
        }
        __syncthreads();
    }

    // ---- outputs: x [B,16] then ljd [B]
    #pragma unroll
    for (int t2 = 0; t2 < 2; ++t2) {
        const float4 vo = *(const float4*)&xls[t2][lane * 4];
        ((float4*)(out + (row0 + t2 * 16) * 16))[lane] = vo;
    }
    #pragma unroll
    for (int t2 = 0; t2 < 2; ++t2) {
        const float v = __shfl(ljrow[t2], (lane & 15) * 4);
        if (lane < 16)
            out[(size_t)B_N * 16 + row0 + t2 * 16 + lane] = v;
    }
}

extern "C" void kernel_launch(void* const* d_in, const int* in_sizes, int n_in,
                              void* d_out, int out_size, void* d_ws, size_t ws_size,
                              hipStream_t stream) {
    const float* x     = (const float*)d_in[0];
    const float* c     = (const float*)d_in[1];
    const float* W1s   = (const float*)d_in[2];
    const float* b1s   = (const float*)d_in[3];
    const float* Whs   = (const float*)d_in[4];
    const float* bhs   = (const float*)d_in[5];
    const float* Wos   = (const float*)d_in[6];
    const float* bos   = (const float*)d_in[7];
    const int*   perms = (const int*)d_in[8];
    float* out = (float*)d_out;
    _Float16* ws = (_Float16*)d_ws;

    prep_kernel<<<dim3(416), dim3(64), 0, stream>>>(W1s, b1s, Whs, Wos, ws);
    flow_mfma<<<dim3(B_N / 32), dim3(64), 0, stream>>>(
        x, c, bhs, bos, perms, ws, out);
}

// Round 7
// 351.292 us; speedup vs baseline: 1.5218x; 1.5218x over previous
//
#include <hip/hip_runtime.h>

#define B_N   262144
#define PMIN_F 0.001f
#define LOG2E 1.44269504088896340736f
#define LN2   0.69314718055994530942f

typedef _Float16 half4v __attribute__((ext_vector_type(4)));
typedef _Float16 half8  __attribute__((ext_vector_type(8)));
typedef float    floatx4 __attribute__((ext_vector_type(4)));

__device__ __forceinline__ float fexp2(float x) { return __builtin_amdgcn_exp2f(x); }
__device__ __forceinline__ float flog2(float x) { return __builtin_amdgcn_logf(x); }
__device__ __forceinline__ float frcp (float x) { return __builtin_amdgcn_rcpf(x); }

// ---------------------------------------------------------------------------
// Prep: weights fp32 -> f16 in MFMA B-fragment order.
// Fragment (ntile, kstep): lane (kg=lane>>4, c=lane&15) holds 8 halves
// B[kstep*32 + kg*8 + j][ntile*16 + c], j=0..7.
//   r in [0,8)   : mm1 W1 16x128, K padded to 32; k==16 row carries b1
//   r in [8,40)  : mm2 Wh 128x128
//   r in [40,104): mm3 Wo 128x248 column-remapped to 256 (31->32 pad per d)
// ---------------------------------------------------------------------------
__global__ __launch_bounds__(64) void prep_kernel(
    const float* __restrict__ W1s, const float* __restrict__ b1s,
    const float* __restrict__ Whs, const float* __restrict__ Wos,
    _Float16* __restrict__ ws)
{
    const int bid   = blockIdx.x;          // 0..415
    const int layer = bid / 104;
    const int r     = bid % 104;
    const int lane  = threadIdx.x;
    const int kg    = lane >> 4;
    const int c     = lane & 15;

    half8 v;
    if (r < 8) {
        const int nt = r, n = nt * 16 + c;
        const float* W1 = W1s + layer * 16 * 128;
        const float* b1 = b1s + layer * 128;
        #pragma unroll
        for (int j = 0; j < 8; ++j) {
            const int k = kg * 8 + j;
            v[j] = (k < 16) ? (_Float16)W1[k * 128 + n]
                 : (k == 16) ? (_Float16)b1[n] : (_Float16)0.f;
        }
    } else if (r < 40) {
        const int f = r - 8, nt = f >> 2, ks = f & 3, n = nt * 16 + c;
        const float* Wh = Whs + layer * 128 * 128;
        #pragma unroll
        for (int j = 0; j < 8; ++j) {
            const int k = ks * 32 + kg * 8 + j;
            v[j] = (_Float16)Wh[k * 128 + n];
        }
    } else {
        const int f = r - 40, nt = f >> 2, ks = f & 3, n = nt * 16 + c;
        const int dd = n >> 5, cc = n & 31;
        const float* Wo = Wos + layer * 128 * 248;
        #pragma unroll
        for (int j = 0; j < 8; ++j) {
            const int k = ks * 32 + kg * 8 + j;
            v[j] = (cc < 31) ? (_Float16)Wo[k * 248 + dd * 31 + cc] : (_Float16)0.f;
        }
    }
    *(half8*)(ws + (size_t)bid * 512 + lane * 8) = v;
}

// ---------------------------------------------------------------------------
// Main: one wave = 32 rows (2 tiles). Single 16x132 R buffer per tile reused
// h1 -> h2 -> theta-half (A-frags pulled to regs before each overwrite);
// mm3+spline split into 2 half-passes (d=0..3, d=4..7).
// LDS/WG = 2*(1KB xls + 256B cls + 4.125KB R) = 11 KB -> 14 WGs/CU.
// NOTE: __launch_bounds__(64) ONLY — a second arg of 4 pins VGPR to 64 and
// spills catastrophically (measured R2: 848us, R6: 473us). Never re-add it.
// ---------------------------------------------------------------------------
__global__ __launch_bounds__(64) void flow_mfma(
    const float* __restrict__ x_in,
    const float* __restrict__ c_in,
    const float* __restrict__ bhs,
    const float* __restrict__ bos,
    const int*   __restrict__ perms,
    const _Float16* __restrict__ wsW,
    float* __restrict__ out)
{
    __shared__ __align__(16) float    xls[2][256];   // [tile][16 rows][16]
    __shared__ __align__(16) _Float16 cls[2][128];   // [tile][16 rows][8]
    __shared__ __align__(16) _Float16 R[2][2112];    // h1 / h2 / theta-half, stride 132

    const int lane = threadIdx.x;
    const int q    = lane >> 4;
    const int m    = lane & 15;
    const long long row0 = (long long)blockIdx.x * 32;

    {
        const float4* xp = (const float4*)(x_in + row0 * 16);
        *(float4*)&xls[0][lane * 4] = xp[lane];
        *(float4*)&xls[1][lane * 4] = xp[lane + 64];
        const float2* cp = (const float2*)(c_in + row0 * 8);
        const float2 c0 = cp[lane], c1 = cp[lane + 64];
        cls[0][lane * 2]     = (_Float16)c0.x;
        cls[0][lane * 2 + 1] = (_Float16)c0.y;
        cls[1][lane * 2]     = (_Float16)c1.x;
        cls[1][lane * 2 + 1] = (_Float16)c1.y;
    }
    __syncthreads();

    float ljrow[2] = {0.f, 0.f};

    for (int l = 0; l < 4; ++l) {
        const _Float16* wsl = wsW + (size_t)l * 104 * 512;
        const float* bh = bhs + l * 128;
        const float* bo = bos + l * 248;

        // ================= mm1: [x1,c,1] @ [W1;b1] -> h1 =================
        half8 a1[2];
        #pragma unroll
        for (int t2 = 0; t2 < 2; ++t2) {
            #pragma unroll
            for (int j = 0; j < 8; ++j) a1[t2][j] = (_Float16)0.f;
            if (q == 0) {
                const float4 lo = *(const float4*)&xls[t2][m * 16];
                const float4 hi = *(const float4*)&xls[t2][m * 16 + 4];
                a1[t2][0] = (_Float16)lo.x; a1[t2][1] = (_Float16)lo.y;
                a1[t2][2] = (_Float16)lo.z; a1[t2][3] = (_Float16)lo.w;
                a1[t2][4] = (_Float16)hi.x; a1[t2][5] = (_Float16)hi.y;
                a1[t2][6] = (_Float16)hi.z; a1[t2][7] = (_Float16)hi.w;
            } else if (q == 1) {
                a1[t2] = *(const half8*)&cls[t2][m * 8];
            } else if (q == 2) {
                a1[t2][0] = (_Float16)1.f;   // k=16 -> bias row
            }
        }
        {
            const floatx4 z = {0.f, 0.f, 0.f, 0.f};
            floatx4 acc0[8], acc1[8];
            #pragma unroll
            for (int nt = 0; nt < 8; ++nt) {
                const half8 b = *(const half8*)(wsl + nt * 512 + lane * 8);
                acc0[nt] = __builtin_amdgcn_mfma_f32_16x16x32_f16(a1[0], b, z, 0, 0, 0);
                acc1[nt] = __builtin_amdgcn_mfma_f32_16x16x32_f16(a1[1], b, z, 0, 0, 0);
            }
            #pragma unroll
            for (int nt = 0; nt < 8; ++nt)
                #pragma unroll
                for (int reg = 0; reg < 4; ++reg) {
                    R[0][(q * 4 + reg) * 132 + nt * 16 + m] = (_Float16)fmaxf(acc0[nt][reg], 0.f);
                    R[1][(q * 4 + reg) * 132 + nt * 16 + m] = (_Float16)fmaxf(acc1[nt][reg], 0.f);
                }
        }
        __syncthreads();

        // ===== mm2: pull h1 A-frags to regs, then overwrite region with h2 =====
        half8 a2[2][4];
        #pragma unroll
        for (int t2 = 0; t2 < 2; ++t2)
            #pragma unroll
            for (int ks = 0; ks < 4; ++ks) {
                const half4v lo = *(const half4v*)&R[t2][m * 132 + ks * 32 + q * 8];
                const half4v hi = *(const half4v*)&R[t2][m * 132 + ks * 32 + q * 8 + 4];
                a2[t2][ks] = __builtin_shufflevector(lo, hi, 0, 1, 2, 3, 4, 5, 6, 7);
            }
        __syncthreads();
        {
            floatx4 acc0[8], acc1[8];
            #pragma unroll
            for (int nt = 0; nt < 8; ++nt) {
                const float bb = bh[nt * 16 + m];
                acc0[nt][0] = bb; acc0[nt][1] = bb; acc0[nt][2] = bb; acc0[nt][3] = bb;
                acc1[nt] = acc0[nt];
            }
            #pragma unroll
            for (int ks = 0; ks < 4; ++ks)
                #pragma unroll
                for (int nt = 0; nt < 8; ++nt) {
                    const half8 b = *(const half8*)(wsl + (8 + nt * 4 + ks) * 512 + lane * 8);
                    acc0[nt] = __builtin_amdgcn_mfma_f32_16x16x32_f16(a2[0][ks], b, acc0[nt], 0, 0, 0);
                    acc1[nt] = __builtin_amdgcn_mfma_f32_16x16x32_f16(a2[1][ks], b, acc1[nt], 0, 0, 0);
                }
            #pragma unroll
            for (int nt = 0; nt < 8; ++nt)
                #pragma unroll
                for (int reg = 0; reg < 4; ++reg) {
                    R[0][(q * 4 + reg) * 132 + nt * 16 + m] = (_Float16)fmaxf(acc0[nt][reg], 0.f);
                    R[1][(q * 4 + reg) * 132 + nt * 16 + m] = (_Float16)fmaxf(acc1[nt][reg], 0.f);
                }
        }
        __syncthreads();

        // ===== mm3: pull h2 A-frags to regs; theta halves overwrite region =====
        half8 a3[2][4];
        #pragma unroll
        for (int t2 = 0; t2 < 2; ++t2)
            #pragma unroll
            for (int ks = 0; ks < 4; ++ks) {
                const half4v lo = *(const half4v*)&R[t2][m * 132 + ks * 32 + q * 8];
                const half4v hi = *(const half4v*)&R[t2][m * 132 + ks * 32 + q * 8 + 4];
                a3[t2][ks] = __builtin_shufflevector(lo, hi, 0, 1, 2, 3, 4, 5, 6, 7);
            }
        __syncthreads();

        #pragma unroll
        for (int hf = 0; hf < 2; ++hf) {
            // ---- mm3 half: cols [hf*128, hf*128+128) = d in [hf*4, hf*4+4)
            {
                floatx4 acc0[8], acc1[8];
                #pragma unroll
                for (int nt8 = 0; nt8 < 8; ++nt8) {
                    const int nt = hf * 8 + nt8;
                    const float bb = ((nt & 1) && m == 15) ? 0.f
                                   : bo[(nt >> 1) * 31 + (nt & 1) * 16 + m];
                    acc0[nt8][0] = bb; acc0[nt8][1] = bb; acc0[nt8][2] = bb; acc0[nt8][3] = bb;
                    acc1[nt8] = acc0[nt8];
                }
                #pragma unroll
                for (int ks = 0; ks < 4; ++ks)
                    #pragma unroll
                    for (int nt8 = 0; nt8 < 8; ++nt8) {
                        const int nt = hf * 8 + nt8;
                        const half8 b = *(const half8*)(wsl + (40 + nt * 4 + ks) * 512 + lane * 8);
                        acc0[nt8] = __builtin_amdgcn_mfma_f32_16x16x32_f16(a3[0][ks], b, acc0[nt8], 0, 0, 0);
                        acc1[nt8] = __builtin_amdgcn_mfma_f32_16x16x32_f16(a3[1][ks], b, acc1[nt8], 0, 0, 0);
                    }
                #pragma unroll
                for (int nt8 = 0; nt8 < 8; ++nt8)
                    #pragma unroll
                    for (int reg = 0; reg < 4; ++reg) {
                        R[0][(q * 4 + reg) * 132 + nt8 * 16 + m] = (_Float16)acc0[nt8][reg];
                        R[1][(q * 4 + reg) * 132 + nt8 * 16 + m] = (_Float16)acc1[nt8][reg];
                    }
            }
            __syncthreads();

            // ---- spline half-pass: 128 items (2 tiles x 16 rows x 4 d)
            #pragma unroll
            for (int itp = 0; itp < 2; ++itp) {
                const int t2   = itp;
                const int row  = lane >> 2;
                const int dloc = lane & 3;
                const int d    = hf * 4 + dloc;
                const int base = row * 132 + dloc * 32;

                const half4v v0 = *(const half4v*)&R[t2][base];
                const half4v v1 = *(const half4v*)&R[t2][base + 4];
                const half4v v2 = *(const half4v*)&R[t2][base + 8];
                const half4v v3 = *(const half4v*)&R[t2][base + 12];
                const half4v v4 = *(const half4v*)&R[t2][base + 16];
                const float x2 = xls[t2][row * 16 + 8 + d];

                float tw[10];
                tw[0]=(float)v0[0]; tw[1]=(float)v0[1]; tw[2]=(float)v0[2]; tw[3]=(float)v0[3];
                tw[4]=(float)v1[0]; tw[5]=(float)v1[1]; tw[6]=(float)v1[2]; tw[7]=(float)v1[3];
                tw[8]=(float)v2[0]; tw[9]=(float)v2[1];

                float cx[11], cy[11];
                {
                    float m1 = tw[0];
                    #pragma unroll
                    for (int i = 1; i < 10; ++i) m1 = fmaxf(m1, tw[i]);
                    float se = 0.f;
                    #pragma unroll
                    for (int i = 0; i < 10; ++i) { tw[i] = fexp2((tw[i] - m1) * LOG2E); se += tw[i]; }
                    const float inv198 = 1.98f * frcp(se);   // 2*(1-PMIN*K)*inv
                    cx[0] = -1.f;
                    #pragma unroll
                    for (int i = 0; i < 10; ++i) cx[i + 1] = cx[i] + fmaf(tw[i], inv198, 0.002f);
                }
                {
                    float t0=(float)v2[2], t1=(float)v2[3];
                    float t2v=(float)v3[0], t3=(float)v3[1], t4=(float)v3[2], t5=(float)v3[3];
                    float t6=(float)v4[0], t7=(float)v4[1], t8=(float)v4[2], t9=(float)v4[3];
                    float hm = fmaxf(fmaxf(fmaxf(t0,t1),fmaxf(t2v,t3)),
                                     fmaxf(fmaxf(t4,t5),fmaxf(fmaxf(t6,t7),fmaxf(t8,t9))));
                    float e0=fexp2((t0-hm)*LOG2E), e1=fexp2((t1-hm)*LOG2E);
                    float e2=fexp2((t2v-hm)*LOG2E), e3=fexp2((t3-hm)*LOG2E);
                    float e4=fexp2((t4-hm)*LOG2E), e5=fexp2((t5-hm)*LOG2E);
                    float e6=fexp2((t6-hm)*LOG2E), e7=fexp2((t7-hm)*LOG2E);
                    float e8=fexp2((t8-hm)*LOG2E), e9=fexp2((t9-hm)*LOG2E);
                    const float se = ((e0+e1)+(e2+e3))+((e4+e5)+((e6+e7)+(e8+e9)));
                    const float inv198 = 1.98f * frcp(se);
                    cy[0] = -1.f;
                    cy[1] = cy[0] + fmaf(e0, inv198, 0.002f);
                    cy[2] = cy[1] + fmaf(e1, inv198, 0.002f);
                    cy[3] = cy[2] + fmaf(e2, inv198, 0.002f);
                    cy[4] = cy[3] + fmaf(e3, inv198, 0.002f);
                    cy[5] = cy[4] + fmaf(e4, inv198, 0.002f);
                    cy[6] = cy[5] + fmaf(e5, inv198, 0.002f);
                    cy[7] = cy[6] + fmaf(e6, inv198, 0.002f);
                    cy[8] = cy[7] + fmaf(e7, inv198, 0.002f);
                    cy[9] = cy[8] + fmaf(e8, inv198, 0.002f);
                    cy[10]= cy[9] + fmaf(e9, inv198, 0.002f);
                }

                int cnt = 0;
                #pragma unroll
                for (int i = 0; i < 11; ++i) cnt += (cx[i] < x2) ? 1 : 0;
                const int bidx = cnt - 1;
                const bool inb = (bidx >= 0) && (bidx < 10);
                const int ci = bidx < 0 ? 0 : (bidx > 9 ? 9 : bidx);

                float xlo = cx[0], xhi = cx[1], ylo = cy[0], yhi = cy[1];
                #pragma unroll
                for (int i = 1; i < 10; ++i) {
                    const bool pick = (i == ci);
                    xlo = pick ? cx[i]     : xlo;
                    xhi = pick ? cx[i + 1] : xhi;
                    ylo = pick ? cy[i]     : ylo;
                    yhi = pick ? cy[i + 1] : yhi;
                }
                const float xw = xhi - xlo, yw = yhi - ylo;
                const float rx = cx[10], ry = cy[10];

                // slopes: LDS-indexed read of the 2 needed raw params
                const float u1 = (float)R[t2][base + 20 + ci];
                const float u2 = (float)R[t2][base + 21 + ci];
                const float t1 = u1 * LOG2E;
                const float t2s = u2 * LOG2E;
                const float dd1 = PMIN_F + 0.999f * ((t1  > 15.f) ? t1  : flog2(1.f + fexp2(t1)));
                const float dd2 = PMIN_F + 0.999f * ((t2s > 15.f) ? t2s : flog2(1.f + fexp2(t2s)));

                const float xs  = inb ? x2 : (xlo + 0.5f * xw);
                const float rxw = frcp(xw);
                const float s   = yw * rxw;
                const float eta = (xs - xlo) * rxw;
                const float rev = 1.f - eta;
                const float er  = eta * rev;
                const float dn  = s + (dd1 + dd2 - 2.f * s) * er;
                const float yrq = ylo + yw * (s * eta * eta + dd1 * er) * frcp(dn);
                const float jn  = s * s * (dd2 * eta * eta + 2.f * s * er + dd1 * rev * rev);
                const float ljx = LN2 * (flog2(jn) - 2.f * flog2(dn));
                const float ylin = (ry + 1.f) * frcp(rx + 1.f) * (x2 + 1.f) - 1.f;

                xls[t2][row * 16 + 8 + d] = inb ? yrq : ylin;

                float lj = inb ? ljx : 0.f;
                lj += __shfl_xor(lj, 1);
                lj += __shfl_xor(lj, 2);
                ljrow[t2] += lj;
            }
            __syncthreads();
        }

        // ================= permutation =================
        {
            const int4 pv = ((const int4*)(perms + l * 16))[lane & 3];
            const int mm = lane >> 2;
            const float a0 = xls[0][mm * 16 + pv.x];
            const float a1v = xls[0][mm * 16 + pv.y];
            const float a2v = xls[0][mm * 16 + pv.z];
            const float a3v = xls[0][mm * 16 + pv.w];
            const float b0 = xls[1][mm * 16 + pv.x];
            const float b1v = xls[1][mm * 16 + pv.y];
            const float b2 = xls[1][mm * 16 + pv.z];
            const float b3 = xls[1][mm * 16 + pv.w];
            __syncthreads();
            *(float4*)&xls[0][lane * 4] = make_float4(a0, a1v, a2v, a3v);
            *(float4*)&xls[1][lane * 4] = make_float4(b0, b1v, b2, b3);
        }
        __syncthreads();
    }

    // ---- outputs: x [B,16] then ljd [B]
    #pragma unroll
    for (int t2 = 0; t2 < 2; ++t2) {
        const float4 vo = *(const float4*)&xls[t2][lane * 4];
        ((float4*)(out + (row0 + t2 * 16) * 16))[lane] = vo;
    }
    #pragma unroll
    for (int t2 = 0; t2 < 2; ++t2) {
        const float v = __shfl(ljrow[t2], (lane & 15) * 4);
        if (lane < 16)
            out[(size_t)B_N * 16 + row0 + t2 * 16 + lane] = v;
    }
}

extern "C" void kernel_launch(void* const* d_in, const int* in_sizes, int n_in,
                              void* d_out, int out_size, void* d_ws, size_t ws_size,
                              hipStream_t stream) {
    const float* x     = (const float*)d_in[0];
    const float* c     = (const float*)d_in[1];
    const float* W1s   = (const float*)d_in[2];
    const float* b1s   = (const float*)d_in[3];
    const float* Whs   = (const float*)d_in[4];
    const float* bhs   = (const float*)d_in[5];
    const float* Wos   = (const float*)d_in[6];
    const float* bos   = (const float*)d_in[7];
    const int*   perms = (const int*)d_in[8];
    float* out = (float*)d_out;
    _Float16* ws = (_Float16*)d_ws;

    prep_kernel<<<dim3(416), dim3(64), 0, stream>>>(W1s, b1s, Whs, Wos, ws);
    flow_mfma<<<dim3(B_N / 32), dim3(64), 0, stream>>>(
        x, c, bhs, bos, perms, ws, out);
}

// Round 8
// 302.624 us; speedup vs baseline: 1.7665x; 1.1608x over previous
//
#include <hip/hip_runtime.h>

#define B_N   262144
#define PMIN_F 0.001f
#define LOG2E 1.44269504088896340736f
#define LN2   0.69314718055994530942f

typedef _Float16 half4v __attribute__((ext_vector_type(4)));
typedef _Float16 half8  __attribute__((ext_vector_type(8)));
typedef float    floatx4 __attribute__((ext_vector_type(4)));

__device__ __forceinline__ float fexp2(float x) { return __builtin_amdgcn_exp2f(x); }
__device__ __forceinline__ float flog2(float x) { return __builtin_amdgcn_logf(x); }
__device__ __forceinline__ float frcp (float x) { return __builtin_amdgcn_rcpf(x); }

// ---------------------------------------------------------------------------
// Prep: weights fp32 -> f16 in MFMA B-fragment order (unchanged).
//   r in [0,8)   : mm1 W1 16x128, K padded to 32; k==16 row carries b1
//   r in [8,40)  : mm2 Wh 128x128
//   r in [40,104): mm3 Wo 128x248 column-remapped to 256 (31->32 pad per d)
// ---------------------------------------------------------------------------
__global__ __launch_bounds__(64) void prep_kernel(
    const float* __restrict__ W1s, const float* __restrict__ b1s,
    const float* __restrict__ Whs, const float* __restrict__ Wos,
    _Float16* __restrict__ ws)
{
    const int bid   = blockIdx.x;          // 0..415
    const int layer = bid / 104;
    const int r     = bid % 104;
    const int lane  = threadIdx.x;
    const int kg    = lane >> 4;
    const int c     = lane & 15;

    half8 v;
    if (r < 8) {
        const int nt = r, n = nt * 16 + c;
        const float* W1 = W1s + layer * 16 * 128;
        const float* b1 = b1s + layer * 128;
        #pragma unroll
        for (int j = 0; j < 8; ++j) {
            const int k = kg * 8 + j;
            v[j] = (k < 16) ? (_Float16)W1[k * 128 + n]
                 : (k == 16) ? (_Float16)b1[n] : (_Float16)0.f;
        }
    } else if (r < 40) {
        const int f = r - 8, nt = f >> 2, ks = f & 3, n = nt * 16 + c;
        const float* Wh = Whs + layer * 128 * 128;
        #pragma unroll
        for (int j = 0; j < 8; ++j) {
            const int k = ks * 32 + kg * 8 + j;
            v[j] = (_Float16)Wh[k * 128 + n];
        }
    } else {
        const int f = r - 40, nt = f >> 2, ks = f & 3, n = nt * 16 + c;
        const int dd = n >> 5, cc = n & 31;
        const float* Wo = Wos + layer * 128 * 248;
        #pragma unroll
        for (int j = 0; j < 8; ++j) {
            const int k = ks * 32 + kg * 8 + j;
            v[j] = (cc < 31) ? (_Float16)Wo[k * 248 + dd * 31 + cc] : (_Float16)0.f;
        }
    }
    *(half8*)(ws + (size_t)bid * 512 + lane * 8) = v;
}

// ---------------------------------------------------------------------------
// Main: one wave = 32 rows (2 tiles). All MFMA sections split into nt-groups
// of 4 so peak accumulator = 32 AGPRs (unified-file budget!).
// Register model (validated R2/R5/R6/R7): occupancy = 512 / (arch VGPR +
// AGPR); __launch_bounds__(64, N) sets total budget 512/N. N=3 -> 170.
// NOTE: never use N=4 (total 128 -> 64 arch -> catastrophic spill).
// LDS/WG = 11 KB -> not binding at 3 waves/SIMD (12 WG/CU = 132 KB).
// ---------------------------------------------------------------------------
__global__ __launch_bounds__(64, 3) void flow_mfma(
    const float* __restrict__ x_in,
    const float* __restrict__ c_in,
    const float* __restrict__ bhs,
    const float* __restrict__ bos,
    const int*   __restrict__ perms,
    const _Float16* __restrict__ wsW,
    float* __restrict__ out)
{
    __shared__ __align__(16) float    xls[2][256];   // [tile][16 rows][16]
    __shared__ __align__(16) _Float16 cls[2][128];   // [tile][16 rows][8]
    __shared__ __align__(16) _Float16 R[2][2112];    // h1 / h2 / theta-half, stride 132

    const int lane = threadIdx.x;
    const int q    = lane >> 4;
    const int m    = lane & 15;
    const long long row0 = (long long)blockIdx.x * 32;

    {
        const float4* xp = (const float4*)(x_in + row0 * 16);
        *(float4*)&xls[0][lane * 4] = xp[lane];
        *(float4*)&xls[1][lane * 4] = xp[lane + 64];
        const float2* cp = (const float2*)(c_in + row0 * 8);
        const float2 c0 = cp[lane], c1 = cp[lane + 64];
        cls[0][lane * 2]     = (_Float16)c0.x;
        cls[0][lane * 2 + 1] = (_Float16)c0.y;
        cls[1][lane * 2]     = (_Float16)c1.x;
        cls[1][lane * 2 + 1] = (_Float16)c1.y;
    }
    __syncthreads();

    // layer-invariant part of the mm1 A-fragment (c data / bias-one)
    half8 a1c[2];
    #pragma unroll
    for (int t2 = 0; t2 < 2; ++t2) {
        #pragma unroll
        for (int j = 0; j < 8; ++j) a1c[t2][j] = (_Float16)0.f;
        if (q == 1)      a1c[t2] = *(const half8*)&cls[t2][m * 8];
        else if (q == 2) a1c[t2][0] = (_Float16)1.f;   // k=16 -> bias row
    }

    float ljrow[2] = {0.f, 0.f};

    for (int l = 0; l < 4; ++l) {
        const _Float16* wsl = wsW + (size_t)l * 104 * 512;
        const float* bh = bhs + l * 128;
        const float* bo = bos + l * 248;

        // ================= mm1: [x1,c,1] @ [W1;b1] -> h1 =================
        half8 a1[2];
        #pragma unroll
        for (int t2 = 0; t2 < 2; ++t2) {
            a1[t2] = a1c[t2];
            if (q == 0) {
                const float4 lo = *(const float4*)&xls[t2][m * 16];
                const float4 hi = *(const float4*)&xls[t2][m * 16 + 4];
                a1[t2][0] = (_Float16)lo.x; a1[t2][1] = (_Float16)lo.y;
                a1[t2][2] = (_Float16)lo.z; a1[t2][3] = (_Float16)lo.w;
                a1[t2][4] = (_Float16)hi.x; a1[t2][5] = (_Float16)hi.y;
                a1[t2][6] = (_Float16)hi.z; a1[t2][7] = (_Float16)hi.w;
            }
        }
        #pragma unroll
        for (int g = 0; g < 2; ++g) {
            const floatx4 z = {0.f, 0.f, 0.f, 0.f};
            floatx4 acc0[4], acc1[4];
            #pragma unroll
            for (int nt = 0; nt < 4; ++nt) {
                const half8 b = *(const half8*)(wsl + (g * 4 + nt) * 512 + lane * 8);
                acc0[nt] = __builtin_amdgcn_mfma_f32_16x16x32_f16(a1[0], b, z, 0, 0, 0);
                acc1[nt] = __builtin_amdgcn_mfma_f32_16x16x32_f16(a1[1], b, z, 0, 0, 0);
            }
            #pragma unroll
            for (int nt = 0; nt < 4; ++nt)
                #pragma unroll
                for (int reg = 0; reg < 4; ++reg) {
                    R[0][(q * 4 + reg) * 132 + (g * 4 + nt) * 16 + m] = (_Float16)fmaxf(acc0[nt][reg], 0.f);
                    R[1][(q * 4 + reg) * 132 + (g * 4 + nt) * 16 + m] = (_Float16)fmaxf(acc1[nt][reg], 0.f);
                }
        }
        __syncthreads();

        // ===== mm2: pull h1 A-frags to regs, then overwrite region with h2 =====
        half8 a2[2][4];
        #pragma unroll
        for (int t2 = 0; t2 < 2; ++t2)
            #pragma unroll
            for (int ks = 0; ks < 4; ++ks) {
                const half4v lo = *(const half4v*)&R[t2][m * 132 + ks * 32 + q * 8];
                const half4v hi = *(const half4v*)&R[t2][m * 132 + ks * 32 + q * 8 + 4];
                a2[t2][ks] = __builtin_shufflevector(lo, hi, 0, 1, 2, 3, 4, 5, 6, 7);
            }
        __syncthreads();
        #pragma unroll
        for (int g = 0; g < 2; ++g) {
            floatx4 acc0[4], acc1[4];
            #pragma unroll
            for (int nt = 0; nt < 4; ++nt) {
                const float bb = bh[(g * 4 + nt) * 16 + m];
                acc0[nt][0] = bb; acc0[nt][1] = bb; acc0[nt][2] = bb; acc0[nt][3] = bb;
                acc1[nt] = acc0[nt];
            }
            #pragma unroll
            for (int ks = 0; ks < 4; ++ks)
                #pragma unroll
                for (int nt = 0; nt < 4; ++nt) {
                    const half8 b = *(const half8*)(wsl + (8 + (g * 4 + nt) * 4 + ks) * 512 + lane * 8);
                    acc0[nt] = __builtin_amdgcn_mfma_f32_16x16x32_f16(a2[0][ks], b, acc0[nt], 0, 0, 0);
                    acc1[nt] = __builtin_amdgcn_mfma_f32_16x16x32_f16(a2[1][ks], b, acc1[nt], 0, 0, 0);
                }
            #pragma unroll
            for (int nt = 0; nt < 4; ++nt)
                #pragma unroll
                for (int reg = 0; reg < 4; ++reg) {
                    R[0][(q * 4 + reg) * 132 + (g * 4 + nt) * 16 + m] = (_Float16)fmaxf(acc0[nt][reg], 0.f);
                    R[1][(q * 4 + reg) * 132 + (g * 4 + nt) * 16 + m] = (_Float16)fmaxf(acc1[nt][reg], 0.f);
                }
        }
        __syncthreads();

        // ===== mm3: pull h2 A-frags to regs; theta halves overwrite region =====
        half8 a3[2][4];
        #pragma unroll
        for (int t2 = 0; t2 < 2; ++t2)
            #pragma unroll
            for (int ks = 0; ks < 4; ++ks) {
                const half4v lo = *(const half4v*)&R[t2][m * 132 + ks * 32 + q * 8];
                const half4v hi = *(const half4v*)&R[t2][m * 132 + ks * 32 + q * 8 + 4];
                a3[t2][ks] = __builtin_shufflevector(lo, hi, 0, 1, 2, 3, 4, 5, 6, 7);
            }
        __syncthreads();

        #pragma unroll
        for (int hf = 0; hf < 2; ++hf) {
            // ---- mm3 half: cols [hf*128, hf*128+128) = d in [hf*4, hf*4+4)
            #pragma unroll
            for (int g = 0; g < 2; ++g) {
                floatx4 acc0[4], acc1[4];
                #pragma unroll
                for (int nt4 = 0; nt4 < 4; ++nt4) {
                    const int nt = hf * 8 + g * 4 + nt4;
                    const float bb = ((nt & 1) && m == 15) ? 0.f
                                   : bo[(nt >> 1) * 31 + (nt & 1) * 16 + m];
                    acc0[nt4][0] = bb; acc0[nt4][1] = bb; acc0[nt4][2] = bb; acc0[nt4][3] = bb;
                    acc1[nt4] = acc0[nt4];
                }
                #pragma unroll
                for (int ks = 0; ks < 4; ++ks)
                    #pragma unroll
                    for (int nt4 = 0; nt4 < 4; ++nt4) {
                        const int nt = hf * 8 + g * 4 + nt4;
                        const half8 b = *(const half8*)(wsl + (40 + nt * 4 + ks) * 512 + lane * 8);
                        acc0[nt4] = __builtin_amdgcn_mfma_f32_16x16x32_f16(a3[0][ks], b, acc0[nt4], 0, 0, 0);
                        acc1[nt4] = __builtin_amdgcn_mfma_f32_16x16x32_f16(a3[1][ks], b, acc1[nt4], 0, 0, 0);
                    }
                #pragma unroll
                for (int nt4 = 0; nt4 < 4; ++nt4)
                    #pragma unroll
                    for (int reg = 0; reg < 4; ++reg) {
                        R[0][(q * 4 + reg) * 132 + (g * 4 + nt4) * 16 + m] = (_Float16)acc0[nt4][reg];
                        R[1][(q * 4 + reg) * 132 + (g * 4 + nt4) * 16 + m] = (_Float16)acc1[nt4][reg];
                    }
            }
            __syncthreads();

            // ---- spline half-pass: 128 items (2 tiles x 16 rows x 4 d)
            #pragma unroll
            for (int itp = 0; itp < 2; ++itp) {
                const int t2   = itp;
                const int row  = lane >> 2;
                const int dloc = lane & 3;
                const int d    = hf * 4 + dloc;
                const int base = row * 132 + dloc * 32;

                const half4v v0 = *(const half4v*)&R[t2][base];
                const half4v v1 = *(const half4v*)&R[t2][base + 4];
                const half4v v2 = *(const half4v*)&R[t2][base + 8];
                const half4v v3 = *(const half4v*)&R[t2][base + 12];
                const half4v v4 = *(const half4v*)&R[t2][base + 16];
                const float x2 = xls[t2][row * 16 + 8 + d];

                float tw[10];
                tw[0]=(float)v0[0]; tw[1]=(float)v0[1]; tw[2]=(float)v0[2]; tw[3]=(float)v0[3];
                tw[4]=(float)v1[0]; tw[5]=(float)v1[1]; tw[6]=(float)v1[2]; tw[7]=(float)v1[3];
                tw[8]=(float)v2[0]; tw[9]=(float)v2[1];

                float cx[11], cy[11];
                {
                    float m1 = tw[0];
                    #pragma unroll
                    for (int i = 1; i < 10; ++i) m1 = fmaxf(m1, tw[i]);
                    float se = 0.f;
                    #pragma unroll
                    for (int i = 0; i < 10; ++i) { tw[i] = fexp2((tw[i] - m1) * LOG2E); se += tw[i]; }
                    const float inv198 = 1.98f * frcp(se);   // 2*(1-PMIN*K)*inv
                    cx[0] = -1.f;
                    #pragma unroll
                    for (int i = 0; i < 10; ++i) cx[i + 1] = cx[i] + fmaf(tw[i], inv198, 0.002f);
                }
                {
                    float t0=(float)v2[2], t1=(float)v2[3];
                    float t2v=(float)v3[0], t3=(float)v3[1], t4=(float)v3[2], t5=(float)v3[3];
                    float t6=(float)v4[0], t7=(float)v4[1], t8=(float)v4[2], t9=(float)v4[3];
                    float hm = fmaxf(fmaxf(fmaxf(t0,t1),fmaxf(t2v,t3)),
                                     fmaxf(fmaxf(t4,t5),fmaxf(fmaxf(t6,t7),fmaxf(t8,t9))));
                    float e0=fexp2((t0-hm)*LOG2E), e1=fexp2((t1-hm)*LOG2E);
                    float e2=fexp2((t2v-hm)*LOG2E), e3=fexp2((t3-hm)*LOG2E);
                    float e4=fexp2((t4-hm)*LOG2E), e5=fexp2((t5-hm)*LOG2E);
                    float e6=fexp2((t6-hm)*LOG2E), e7=fexp2((t7-hm)*LOG2E);
                    float e8=fexp2((t8-hm)*LOG2E), e9=fexp2((t9-hm)*LOG2E);
                    const float se = ((e0+e1)+(e2+e3))+((e4+e5)+((e6+e7)+(e8+e9)));
                    const float inv198 = 1.98f * frcp(se);
                    cy[0] = -1.f;
                    cy[1] = cy[0] + fmaf(e0, inv198, 0.002f);
                    cy[2] = cy[1] + fmaf(e1, inv198, 0.002f);
                    cy[3] = cy[2] + fmaf(e2, inv198, 0.002f);
                    cy[4] = cy[3] + fmaf(e3, inv198, 0.002f);
                    cy[5] = cy[4] + fmaf(e4, inv198, 0.002f);
                    cy[6] = cy[5] + fmaf(e5, inv198, 0.002f);
                    cy[7] = cy[6] + fmaf(e6, inv198, 0.002f);
                    cy[8] = cy[7] + fmaf(e7, inv198, 0.002f);
                    cy[9] = cy[8] + fmaf(e8, inv198, 0.002f);
                    cy[10]= cy[9] + fmaf(e9, inv198, 0.002f);
                }

                int cnt = 0;
                #pragma unroll
                for (int i = 0; i < 11; ++i) cnt += (cx[i] < x2) ? 1 : 0;
                const int bidx = cnt - 1;
                const bool inb = (bidx >= 0) && (bidx < 10);
                const int ci = bidx < 0 ? 0 : (bidx > 9 ? 9 : bidx);

                float xlo = cx[0], xhi = cx[1], ylo = cy[0], yhi = cy[1];
                #pragma unroll
                for (int i = 1; i < 10; ++i) {
                    const bool pick = (i == ci);
                    xlo = pick ? cx[i]     : xlo;
                    xhi = pick ? cx[i + 1] : xhi;
                    ylo = pick ? cy[i]     : ylo;
                    yhi = pick ? cy[i + 1] : yhi;
                }
                const float xw = xhi - xlo, yw = yhi - ylo;
                const float rx = cx[10], ry = cy[10];

                // slopes: LDS-indexed read of the 2 needed raw params
                const float u1 = (float)R[t2][base + 20 + ci];
                const float u2 = (float)R[t2][base + 21 + ci];
                const float t1 = u1 * LOG2E;
                const float t2s = u2 * LOG2E;
                const float dd1 = PMIN_F + 0.999f * ((t1  > 15.f) ? t1  : flog2(1.f + fexp2(t1)));
                const float dd2 = PMIN_F + 0.999f * ((t2s > 15.f) ? t2s : flog2(1.f + fexp2(t2s)));

                const float xs  = inb ? x2 : (xlo + 0.5f * xw);
                const float rxw = frcp(xw);
                const float s   = yw * rxw;
                const float eta = (xs - xlo) * rxw;
                const float rev = 1.f - eta;
                const float er  = eta * rev;
                const float dn  = s + (dd1 + dd2 - 2.f * s) * er;
                const float yrq = ylo + yw * (s * eta * eta + dd1 * er) * frcp(dn);
                const float jn  = s * s * (dd2 * eta * eta + 2.f * s * er + dd1 * rev * rev);
                const float ljx = LN2 * (flog2(jn) - 2.f * flog2(dn));
                const float ylin = (ry + 1.f) * frcp(rx + 1.f) * (x2 + 1.f) - 1.f;

                xls[t2][row * 16 + 8 + d] = inb ? yrq : ylin;

                float lj = inb ? ljx : 0.f;
                lj += __shfl_xor(lj, 1);
                lj += __shfl_xor(lj, 2);
                ljrow[t2] += lj;
            }
            __syncthreads();
        }

        // ================= permutation =================
        {
            const int4 pv = ((const int4*)(perms + l * 16))[lane & 3];
            const int mm = lane >> 2;
            const float a0 = xls[0][mm * 16 + pv.x];
            const float a1v = xls[0][mm * 16 + pv.y];
            const float a2v = xls[0][mm * 16 + pv.z];
            const float a3v = xls[0][mm * 16 + pv.w];
            const float b0 = xls[1][mm * 16 + pv.x];
            const float b1v = xls[1][mm * 16 + pv.y];
            const float b2 = xls[1][mm * 16 + pv.z];
            const float b3 = xls[1][mm * 16 + pv.w];
            __syncthreads();
            *(float4*)&xls[0][lane * 4] = make_float4(a0, a1v, a2v, a3v);
            *(float4*)&xls[1][lane * 4] = make_float4(b0, b1v, b2, b3);
        }
        __syncthreads();
    }

    // ---- outputs: x [B,16] then ljd [B]
    #pragma unroll
    for (int t2 = 0; t2 < 2; ++t2) {
        const float4 vo = *(const float4*)&xls[t2][lane * 4];
        ((float4*)(out + (row0 + t2 * 16) * 16))[lane] = vo;
    }
    #pragma unroll
    for (int t2 = 0; t2 < 2; ++t2) {
        const float v = __shfl(ljrow[t2], (lane & 15) * 4);
        if (lane < 16)
            out[(size_t)B_N * 16 + row0 + t2 * 16 + lane] = v;
    }
}

extern "C" void kernel_launch(void* const* d_in, const int* in_sizes, int n_in,
                              void* d_out, int out_size, void* d_ws, size_t ws_size,
                              hipStream_t stream) {
    const float* x     = (const float*)d_in[0];
    const float* c     = (const float*)d_in[1];
    const float* W1s   = (const float*)d_in[2];
    const float* b1s   = (const float*)d_in[3];
    const float* Whs   = (const float*)d_in[4];
    const float* bhs   = (const float*)d_in[5];
    const float* Wos   = (const float*)d_in[6];
    const float* bos   = (const float*)d_in[7];
    const int*   perms = (const int*)d_in[8];
    float* out = (float*)d_out;
    _Float16* ws = (_Float16*)d_ws;

    prep_kernel<<<dim3(416), dim3(64), 0, stream>>>(W1s, b1s, Whs, Wos, ws);
    flow_mfma<<<dim3(B_N / 32), dim3(64), 0, stream>>>(
        x, c, bhs, bos, perms, ws, out);
}